// Round 3
// baseline (128.423 us; speedup 1.0000x reference)
//
#include <hip/hip_runtime.h>

#define EMBED 256
#define NUM_DEPTH 128

typedef __attribute__((ext_vector_type(8))) short bf16x8;
typedef __attribute__((ext_vector_type(4))) float f32x4;

__device__ __forceinline__ unsigned short f2b(float f) {
    union { float f; unsigned u; } c; c.f = f;
    unsigned u = c.u;
    u += 0x7fffu + ((u >> 16) & 1u);   // RNE to bf16
    return (unsigned short)(u >> 16);
}
__device__ __forceinline__ float b2f(unsigned short h) {
    union { unsigned u; float f; } c; c.u = ((unsigned)h) << 16;
    return c.f;
}

// ---------------- Phase 1: fp32 -> bf16 conversion of key & value ----------------
__global__ __launch_bounds__(256) void cvt_kernel(
    const float4* __restrict__ key, const float4* __restrict__ val,
    ushort4* __restrict__ kb, ushort4* __restrict__ vb, int n4)
{
    int i = blockIdx.x * blockDim.x + threadIdx.x;
    if (i >= n4) return;
    float4 a = key[i];
    float4 b = val[i];
    kb[i] = make_ushort4(f2b(a.x), f2b(a.y), f2b(a.z), f2b(a.w));
    vb[i] = make_ushort4(f2b(b.x), f2b(b.y), f2b(b.z), f2b(b.w));
}

// ---------------- Phase 2: bin depths by iy0, init out = identity ----------------
// One block per query q, 128 threads (one per depth d).
// dlist[q][*]: d's sorted by bin b = clamp(iy0,-1,H)+1; offs[q][b] = exclusive prefix.
// pxy[q][pos] caches (px,py) in dlist order for coalesced-ish re-reads.
__global__ __launch_bounds__(128) void bin_kernel(
    const float* __restrict__ ref3d, const float* __restrict__ identity,
    const int* __restrict__ spatial,
    unsigned char* __restrict__ dlist, unsigned short* __restrict__ offs,
    int offs_stride, float2* __restrict__ pxy, float* __restrict__ out)
{
    const int q = blockIdx.x;
    const int d = threadIdx.x;
    const int H = spatial[0], W = spatial[1];
    const int l = q * NUM_DEPTH + d;

    const float2 r2 = reinterpret_cast<const float2*>(ref3d)[l];
    const float px = r2.x * (float)W - 0.5f;
    const float py = r2.y * (float)H - 0.5f;
    const int iy0 = (int)floorf(py);
    const int b = min(max(iy0, -1), H) + 1;   // [0, H+1]

    __shared__ unsigned int cnt[132];
    __shared__ unsigned int base[132];
    for (int i = d; i < H + 2; i += NUM_DEPTH) cnt[i] = 0;
    __syncthreads();
    const unsigned pos_in_bin = atomicAdd(&cnt[b], 1u);
    __syncthreads();
    if (d == 0) {
        unsigned s = 0;
        for (int i = 0; i < H + 2; ++i) { base[i] = s; s += cnt[i]; }
        base[H + 2] = s;
    }
    __syncthreads();
    for (int i = d; i < H + 3; i += NUM_DEPTH)
        offs[(size_t)q * offs_stride + i] = (unsigned short)base[i];
    const unsigned pos = base[b] + pos_in_bin;
    dlist[(size_t)q * NUM_DEPTH + pos] = (unsigned char)d;
    pxy[(size_t)q * NUM_DEPTH + pos] = make_float2(px, py);
    out[l] = identity[l];
}

// ---------------- Phase 3: fused GEMM + bilinear scatter-accumulate --------------
// Block (i=blockIdx.y, j=blockIdx.x): computes D-tile = key[128i..)x value[128j..)^T
// into LDS (bf16), then processes all (q,d) whose taps fall in image rows
// [Rt*j, Rt*j+Rt), atomically adding w*D/16 into out (pre-set to identity).
__global__ __launch_bounds__(256) void fused_kernel(
    const unsigned short* __restrict__ A,   // kb [nq][256]
    const unsigned short* __restrict__ B,   // vb [nv][256]
    const unsigned char* __restrict__ dlist,
    const unsigned short* __restrict__ offs, int offs_stride,
    const float2* __restrict__ pxy,
    const int* __restrict__ spatial,
    float* __restrict__ out)
{
    __shared__ __align__(16) unsigned short As[128 * 32];
    __shared__ __align__(16) unsigned short Bs[128 * 32];
    __shared__ __align__(16) unsigned short Dt[128 * 128];
    __shared__ unsigned int scanbuf[128];
    __shared__ unsigned int qpref[129];
    __shared__ unsigned int qstart[128];

    const int H = spatial[0], W = spatial[1];
    const int Rt = 128 / W;                 // image rows per p-tile (2 for W=64)
    const int m0 = blockIdx.y * 128;        // q base
    const int jt = blockIdx.x;              // p-tile index
    const int n0 = jt * 128;                // p base
    const int iy_lo = Rt * jt;              // first image row in this tile

    const int tid  = threadIdx.x;
    const int lane = tid & 63;
    const int wave = tid >> 6;
    const int wm = (wave & 1) * 64;
    const int wn = (wave >> 1) * 64;

    f32x4 acc[4][4] = {};

    const int srow = lane >> 2;
    const int scol = (lane & 3) * 8;
    const int k8 = (lane >> 4) * 8;
    const int fm = lane & 15;

    // ---- GEMM main loop (identical structure to validated R2 kernel) ----
    for (int kt = 0; kt < EMBED; kt += 32) {
        #pragma unroll
        for (int t = 0; t < 2; ++t) {
            const int c = wave * 2 + t;
            const int row = c * 16 + srow;
            const unsigned short* ga = A + (size_t)(m0 + row) * EMBED + kt + scol;
            const unsigned short* gb = B + (size_t)(n0 + row) * EMBED + kt + scol;
            __builtin_amdgcn_global_load_lds(
                (const __attribute__((address_space(1))) void*)ga,
                (__attribute__((address_space(3))) void*)(As + c * 512), 16, 0, 0);
            __builtin_amdgcn_global_load_lds(
                (const __attribute__((address_space(1))) void*)gb,
                (__attribute__((address_space(3))) void*)(Bs + c * 512), 16, 0, 0);
        }
        __syncthreads();

        bf16x8 af[4], bfr[4];
        #pragma unroll
        for (int i = 0; i < 4; ++i) {
            af[i]  = *(const bf16x8*)(As + (wm + i * 16 + fm) * 32 + k8);
            bfr[i] = *(const bf16x8*)(Bs + (wn + i * 16 + fm) * 32 + k8);
        }
        #pragma unroll
        for (int i = 0; i < 4; ++i)
            #pragma unroll
            for (int j = 0; j < 4; ++j)
                acc[i][j] = __builtin_amdgcn_mfma_f32_16x16x32_bf16(af[i], bfr[j], acc[i][j], 0, 0, 0);
        __syncthreads();
    }

    // ---- Per-q tap ranges (overlap global loads with epilogue LDS writes) ----
    unsigned my_s = 0, my_e = 0;
    if (tid < 128) {
        const size_t ob = (size_t)(m0 + tid) * offs_stride;
        my_s = offs[ob + Rt * jt];
        my_e = offs[ob + Rt * jt + Rt + 1];
    }

    // ---- Epilogue: D-tile -> LDS (bf16). C/D layout: col=lane&15, row=(lane>>4)*4+r
    const int col = lane & 15;
    const int rbase = (lane >> 4) * 4;
    #pragma unroll
    for (int i = 0; i < 4; ++i)
        #pragma unroll
        for (int j = 0; j < 4; ++j) {
            const int rr = wm + i * 16 + rbase;
            const int cc = wn + j * 16 + col;
            #pragma unroll
            for (int r = 0; r < 4; ++r)
                Dt[(rr + r) * 128 + cc] = f2b(acc[i][j][r]);
        }

    if (tid < 128) { qstart[tid] = my_s; scanbuf[tid] = my_e - my_s; }
    __syncthreads();

    // ---- Hillis-Steele prefix over 128 per-q lengths ----
    #pragma unroll
    for (int off = 1; off < 128; off <<= 1) {
        unsigned v = (tid < 128 && tid >= off) ? scanbuf[tid - off] : 0u;
        __syncthreads();
        if (tid < 128) scanbuf[tid] += v;
        __syncthreads();
    }
    if (tid < 128) qpref[tid + 1] = scanbuf[tid];
    if (tid == 0) qpref[0] = 0;
    __syncthreads();

    const unsigned T = qpref[128];
    for (unsigned e = tid; e < T; e += 256) {
        // binary search for q: qpref[q] <= e < qpref[q+1]
        int lo = 0, hi = 127;
        while (lo < hi) {
            const int mid = (lo + hi + 1) >> 1;
            if (qpref[mid] <= e) lo = mid; else hi = mid - 1;
        }
        const int q = lo;
        const unsigned pos = qstart[q] + (e - qpref[q]);
        const size_t rowb = (size_t)(m0 + q) * NUM_DEPTH;
        const int d = dlist[rowb + pos];
        const float2 c2 = pxy[rowb + pos];
        const float px = c2.x, py = c2.y;
        const float x0f = floorf(px), y0f = floorf(py);
        const int ix0 = (int)x0f, iy0 = (int)y0f;
        const float wx1 = px - x0f, wx0 = 1.0f - wx1;
        const float wy1 = py - y0f, wy0 = 1.0f - wy1;

        float accv = 0.f;
        bool hit = false;
        #pragma unroll
        for (int ky = 0; ky < 2; ++ky) {
            const int iy = iy0 + ky;
            if (iy < iy_lo || iy >= iy_lo + Rt) continue;   // row not in this tile
            const float wy = ky ? wy1 : wy0;
            const int base_p = q * 128 + (iy - iy_lo) * W;
            if (ix0 >= 0 && ix0 < W) { accv = fmaf(wy * wx0, b2f(Dt[base_p + ix0]), accv); hit = true; }
            const int ix1 = ix0 + 1;
            if (ix1 >= 0 && ix1 < W) { accv = fmaf(wy * wx1, b2f(Dt[base_p + ix1]), accv); hit = true; }
        }
        if (hit)
            atomicAdd(&out[(size_t)(m0 + q) * NUM_DEPTH + d], accv * 0.0625f);
    }
}

// ---------------- Fallback (round-1 direct kernel) for small ws ----------------
__global__ __launch_bounds__(256) void uv_direct_kernel(
    const float* __restrict__ key, const float* __restrict__ value,
    const float* __restrict__ identity, const float* __restrict__ ref3d,
    const int* __restrict__ spatial, float* __restrict__ out)
{
    const int q = blockIdx.x;
    const int tid = threadIdx.x;
    const int lane = tid & 63;
    const int wave = tid >> 6;
    const int H = spatial[0], W = spatial[1];
    const int row4 = EMBED / 4;
    const float4 k4 = reinterpret_cast<const float4*>(key + (size_t)q * EMBED)[lane];
    const float4* __restrict__ v4 = reinterpret_cast<const float4*>(value);
    for (int d = wave; d < NUM_DEPTH; d += 4) {
        const int l = q * NUM_DEPTH + d;
        const float rx = ref3d[2 * l], ry = ref3d[2 * l + 1];
        const float px = rx * (float)W - 0.5f, py = ry * (float)H - 0.5f;
        const float x0f = floorf(px), y0f = floorf(py);
        const int ix0 = (int)x0f, iy0 = (int)y0f, ix1 = ix0 + 1, iy1 = iy0 + 1;
        const float wx1 = px - x0f, wx0 = 1.f - wx1, wy1 = py - y0f, wy0 = 1.f - wy1;
        float4 acc = make_float4(0.f, 0.f, 0.f, 0.f);
        #define TAP(IY, IX, WGT) \
            if ((IY) >= 0 && (IY) < H && (IX) >= 0 && (IX) < W) { \
                const float w_ = (WGT); \
                const float4 t = v4[(size_t)((IY) * W + (IX)) * row4 + lane]; \
                acc.x = fmaf(w_, t.x, acc.x); acc.y = fmaf(w_, t.y, acc.y); \
                acc.z = fmaf(w_, t.z, acc.z); acc.w = fmaf(w_, t.w, acc.w); }
        TAP(iy0, ix0, wy0 * wx0) TAP(iy0, ix1, wy0 * wx1)
        TAP(iy1, ix0, wy1 * wx0) TAP(iy1, ix1, wy1 * wx1)
        #undef TAP
        float partial = acc.x * k4.x + acc.y * k4.y + acc.z * k4.z + acc.w * k4.w;
        #pragma unroll
        for (int off = 32; off > 0; off >>= 1) partial += __shfl_xor(partial, off, 64);
        if (lane == 0) out[l] = fmaf(partial, 0.0625f, identity[l]);
    }
}

extern "C" void kernel_launch(void* const* d_in, const int* in_sizes, int n_in,
                              void* d_out, int out_size, void* d_ws, size_t ws_size,
                              hipStream_t stream) {
    // inputs: 0 query(unused) 1 key 2 value 3 identity 4 ref_3d 5 spatial 6 W_attn(unused) 7 b_attn(unused)
    const float* key      = (const float*)d_in[1];
    const float* value    = (const float*)d_in[2];
    const float* identity = (const float*)d_in[3];
    const float* ref3d    = (const float*)d_in[4];
    const int*   spatial  = (const int*)d_in[5];
    float* out = (float*)d_out;

    const int nq = in_sizes[3] / NUM_DEPTH;   // 4096 queries
    const int nv = in_sizes[1] / EMBED;       // 4096 pixels (= H*W)
    const int OFFS_STRIDE = 131;              // supports H up to 128

    // ws layout (256B-aligned chunks)
    const size_t kb_b   = ((size_t)nq * EMBED * 2 + 255) & ~(size_t)255;
    const size_t vb_b   = ((size_t)nv * EMBED * 2 + 255) & ~(size_t)255;
    const size_t dl_b   = ((size_t)nq * NUM_DEPTH + 255) & ~(size_t)255;
    const size_t of_b   = ((size_t)nq * OFFS_STRIDE * 2 + 255) & ~(size_t)255;
    const size_t px_b   = ((size_t)nq * NUM_DEPTH * 8 + 255) & ~(size_t)255;
    const size_t need = kb_b + vb_b + dl_b + of_b + px_b;

    if (ws_size < need || (nq % 128) || (nv % 128)) {
        uv_direct_kernel<<<nq, 256, 0, stream>>>(key, value, identity, ref3d, spatial, out);
        return;
    }

    char* p = (char*)d_ws;
    unsigned short* kb   = (unsigned short*)p;           p += kb_b;
    unsigned short* vb   = (unsigned short*)p;           p += vb_b;
    unsigned char*  dlist= (unsigned char*)p;            p += dl_b;
    unsigned short* offs = (unsigned short*)p;           p += of_b;
    float2*         pxy  = (float2*)p;

    // Phase 1: convert key & value to bf16
    const int n4 = nq * EMBED / 4;
    cvt_kernel<<<(n4 + 255) / 256, 256, 0, stream>>>(
        (const float4*)key, (const float4*)value, (ushort4*)kb, (ushort4*)vb, n4);

    // Phase 2: bin depths by iy0 + out = identity
    bin_kernel<<<nq, NUM_DEPTH, 0, stream>>>(
        ref3d, identity, spatial, dlist, offs, OFFS_STRIDE, pxy, out);

    // Phase 3: fused GEMM + scatter-accumulate
    dim3 grid(nv / 128, nq / 128);
    fused_kernel<<<grid, 256, 0, stream>>>(
        kb, vb, dlist, offs, OFFS_STRIDE, pxy, spatial, out);
}

// Round 4
// 99.002 us; speedup vs baseline: 1.2972x; 1.2972x over previous
//
#include <hip/hip_runtime.h>

#define EMBED 256
#define NUM_DEPTH 128
#define CT_STRIDE 136   // 128 + 8 pad: keeps 16B alignment (272B rows), breaks pow-2 bank stride

typedef __attribute__((ext_vector_type(8))) short bf16x8;
typedef __attribute__((ext_vector_type(4))) float f32x4;

__device__ __forceinline__ unsigned short f2b(float f) {
    union { float f; unsigned u; } c; c.f = f;
    unsigned u = c.u;
    u += 0x7fffu + ((u >> 16) & 1u);   // RNE to bf16
    return (unsigned short)(u >> 16);
}
__device__ __forceinline__ float b2f(unsigned short h) {
    union { unsigned u; float f; } c; c.u = ((unsigned)h) << 16;
    return c.f;
}

// ---------------- Phase 1: fp32 -> bf16 conversion of key & value ----------------
__global__ __launch_bounds__(256) void cvt_kernel(
    const float4* __restrict__ key, const float4* __restrict__ val,
    ushort4* __restrict__ kb, ushort4* __restrict__ vb, int n4)
{
    int i = blockIdx.x * blockDim.x + threadIdx.x;
    if (i >= n4) return;
    float4 a = key[i];
    float4 b = val[i];
    kb[i] = make_ushort4(f2b(a.x), f2b(a.y), f2b(a.z), f2b(a.w));
    vb[i] = make_ushort4(f2b(b.x), f2b(b.y), f2b(b.z), f2b(b.w));
}

// ---------------- Phase 2: D[q][p] = sum_e key[q,e]*value[p,e]  (NT GEMM) --------
// 128x128 tile per block, 256 threads (4 waves, 2x2), 16x16x32 bf16 MFMA,
// global_load_lds width-16 staging (m97 structure). Epilogue repacks the C-tile
// through LDS (aliased over As/Bs) for coalesced dwordx4 stores.
__global__ __launch_bounds__(256) void gemm_nt_bf16(
    const unsigned short* __restrict__ A,   // key bf16 [M][256]
    const unsigned short* __restrict__ B,   // value bf16 [N][256]
    unsigned short* __restrict__ D,         // [M][N] bf16
    int N)
{
    __shared__ __align__(16) unsigned short Ct[128 * CT_STRIDE];  // 34816 B
    unsigned short* As = Ct;              // [128*32] = 8 KB (aliased; dead after K-loop)
    unsigned short* Bs = Ct + 128 * 32;   // next 8 KB

    const int m0 = blockIdx.y * 128;
    const int n0 = blockIdx.x * 128;
    const int tid  = threadIdx.x;
    const int lane = tid & 63;
    const int wave = tid >> 6;
    const int wm = (wave & 1) * 64;
    const int wn = (wave >> 1) * 64;

    f32x4 acc[4][4] = {};

    const int srow = lane >> 2;
    const int scol = (lane & 3) * 8;
    const int k8 = (lane >> 4) * 8;
    const int fm = lane & 15;

    for (int kt = 0; kt < EMBED; kt += 32) {
        #pragma unroll
        for (int t = 0; t < 2; ++t) {
            const int c = wave * 2 + t;
            const int row = c * 16 + srow;
            const unsigned short* ga = A + (size_t)(m0 + row) * EMBED + kt + scol;
            const unsigned short* gb = B + (size_t)(n0 + row) * EMBED + kt + scol;
            __builtin_amdgcn_global_load_lds(
                (const __attribute__((address_space(1))) void*)ga,
                (__attribute__((address_space(3))) void*)(As + c * 512), 16, 0, 0);
            __builtin_amdgcn_global_load_lds(
                (const __attribute__((address_space(1))) void*)gb,
                (__attribute__((address_space(3))) void*)(Bs + c * 512), 16, 0, 0);
        }
        __syncthreads();

        bf16x8 af[4], bfr[4];
        #pragma unroll
        for (int i = 0; i < 4; ++i) {
            af[i]  = *(const bf16x8*)(As + (wm + i * 16 + fm) * 32 + k8);
            bfr[i] = *(const bf16x8*)(Bs + (wn + i * 16 + fm) * 32 + k8);
        }
        #pragma unroll
        for (int i = 0; i < 4; ++i)
            #pragma unroll
            for (int j = 0; j < 4; ++j)
                acc[i][j] = __builtin_amdgcn_mfma_f32_16x16x32_bf16(af[i], bfr[j], acc[i][j], 0, 0, 0);
        __syncthreads();   // also makes As/Bs dead -> Ct reuse below is safe
    }

    // ---- Epilogue: fragments -> Ct (bf16), then coalesced dwordx4 stores ----
    // C/D layout: col=lane&15, row=(lane>>4)*4+r
    const int col = lane & 15;
    const int rbase = (lane >> 4) * 4;
    #pragma unroll
    for (int i = 0; i < 4; ++i)
        #pragma unroll
        for (int j = 0; j < 4; ++j) {
            const int rr = wm + i * 16 + rbase;
            const int cc = wn + j * 16 + col;
            #pragma unroll
            for (int r = 0; r < 4; ++r)
                Ct[(rr + r) * CT_STRIDE + cc] = f2b(acc[i][j][r]);
        }
    __syncthreads();

    #pragma unroll
    for (int it = 0; it < 8; ++it) {
        const int r  = it * 16 + (tid >> 4);   // 0..127
        const int c8 = (tid & 15) * 8;         // 8-ushort chunk
        const int4 v = *(const int4*)(Ct + r * CT_STRIDE + c8);
        *(int4*)(D + (size_t)(m0 + r) * N + n0 + c8) = v;
    }
}

// ---------------- Phase 3: bilinear gather (LDS-staged D rows) + identity -------
// One block per 2 queries; stage both 8 KB D-rows into LDS coalesced, then each
// thread computes one output element with 4 ds_read taps.
__global__ __launch_bounds__(256) void gather_kernel(
    const unsigned short* __restrict__ D,   // [nq][nv] bf16
    const float* __restrict__ identity,     // [nq*128]
    const float* __restrict__ ref3d,        // [nq*128][2]
    const int*   __restrict__ spatial,      // {H, W}
    float* __restrict__ out, int nv)
{
    __shared__ unsigned short Ds[2 * 4096];  // 16 KB (nv <= 4096 guarded on host)

    const int q0 = blockIdx.x * 2;
    const int tid = threadIdx.x;

    // coalesced stage: 2*nv ushorts = 4*nv bytes
    const int4* src = (const int4*)(D + (size_t)q0 * nv);
    int4* dst = (int4*)Ds;
    const int nchunk = (2 * nv) / 8;
    for (int i = tid; i < nchunk; i += 256) dst[i] = src[i];
    __syncthreads();

    const int Hs = spatial[0], Ws = spatial[1];
    const int l = q0 * NUM_DEPTH + tid;      // 256 threads == 2 q * 128 d
    const int qi = tid >> 7;                  // 0 or 1

    const float2 r2 = reinterpret_cast<const float2*>(ref3d)[l];
    const float px = r2.x * (float)Ws - 0.5f;
    const float py = r2.y * (float)Hs - 0.5f;
    const float x0f = floorf(px), y0f = floorf(py);
    const int ix0 = (int)x0f, iy0 = (int)y0f;
    const int ix1 = ix0 + 1,  iy1 = iy0 + 1;
    const float wx1 = px - x0f, wx0 = 1.0f - wx1;
    const float wy1 = py - y0f, wy0 = 1.0f - wy1;
    const bool vx0 = (ix0 >= 0) & (ix0 < Ws);
    const bool vx1 = (ix1 >= 0) & (ix1 < Ws);

    const unsigned short* row = Ds + qi * nv;
    float acc = 0.f;
    if (iy0 >= 0 && iy0 < Hs) {
        if (vx0) acc = fmaf(wy0 * wx0, b2f(row[iy0 * Ws + ix0]), acc);
        if (vx1) acc = fmaf(wy0 * wx1, b2f(row[iy0 * Ws + ix1]), acc);
    }
    if (iy1 >= 0 && iy1 < Hs) {
        if (vx0) acc = fmaf(wy1 * wx0, b2f(row[iy1 * Ws + ix0]), acc);
        if (vx1) acc = fmaf(wy1 * wx1, b2f(row[iy1 * Ws + ix1]), acc);
    }
    out[l] = fmaf(acc, 0.0625f, identity[l]);  // 1/sqrt(256) = 1/16
}

// ---------------- Fallback (round-1 direct kernel) ----------------
__global__ __launch_bounds__(256) void uv_direct_kernel(
    const float* __restrict__ key, const float* __restrict__ value,
    const float* __restrict__ identity, const float* __restrict__ ref3d,
    const int* __restrict__ spatial, float* __restrict__ out)
{
    const int q = blockIdx.x;
    const int tid = threadIdx.x;
    const int lane = tid & 63;
    const int wave = tid >> 6;
    const int H = spatial[0], W = spatial[1];
    const int row4 = EMBED / 4;
    const float4 k4 = reinterpret_cast<const float4*>(key + (size_t)q * EMBED)[lane];
    const float4* __restrict__ v4 = reinterpret_cast<const float4*>(value);
    for (int d = wave; d < NUM_DEPTH; d += 4) {
        const int l = q * NUM_DEPTH + d;
        const float rx = ref3d[2 * l], ry = ref3d[2 * l + 1];
        const float px = rx * (float)W - 0.5f, py = ry * (float)H - 0.5f;
        const float x0f = floorf(px), y0f = floorf(py);
        const int ix0 = (int)x0f, iy0 = (int)y0f, ix1 = ix0 + 1, iy1 = iy0 + 1;
        const float wx1 = px - x0f, wx0 = 1.f - wx1, wy1 = py - y0f, wy0 = 1.f - wy1;
        float4 acc = make_float4(0.f, 0.f, 0.f, 0.f);
        #define TAP(IY, IX, WGT) \
            if ((IY) >= 0 && (IY) < H && (IX) >= 0 && (IX) < W) { \
                const float w_ = (WGT); \
                const float4 t = v4[(size_t)((IY) * W + (IX)) * row4 + lane]; \
                acc.x = fmaf(w_, t.x, acc.x); acc.y = fmaf(w_, t.y, acc.y); \
                acc.z = fmaf(w_, t.z, acc.z); acc.w = fmaf(w_, t.w, acc.w); }
        TAP(iy0, ix0, wy0 * wx0) TAP(iy0, ix1, wy0 * wx1)
        TAP(iy1, ix0, wy1 * wx0) TAP(iy1, ix1, wy1 * wx1)
        #undef TAP
        float partial = acc.x * k4.x + acc.y * k4.y + acc.z * k4.z + acc.w * k4.w;
        #pragma unroll
        for (int off = 32; off > 0; off >>= 1) partial += __shfl_xor(partial, off, 64);
        if (lane == 0) out[l] = fmaf(partial, 0.0625f, identity[l]);
    }
}

extern "C" void kernel_launch(void* const* d_in, const int* in_sizes, int n_in,
                              void* d_out, int out_size, void* d_ws, size_t ws_size,
                              hipStream_t stream) {
    // inputs: 0 query(unused) 1 key 2 value 3 identity 4 ref_3d 5 spatial 6 W_attn(unused) 7 b_attn(unused)
    const float* key      = (const float*)d_in[1];
    const float* value    = (const float*)d_in[2];
    const float* identity = (const float*)d_in[3];
    const float* ref3d    = (const float*)d_in[4];
    const int*   spatial  = (const int*)d_in[5];
    float* out = (float*)d_out;

    const int nq = in_sizes[3] / NUM_DEPTH;   // 4096 queries
    const int nv = in_sizes[1] / EMBED;       // 4096 pixels (= H*W)

    const size_t d_bytes  = (size_t)nq * nv * sizeof(unsigned short);
    const size_t kb_bytes = (size_t)nq * EMBED * sizeof(unsigned short);
    const size_t vb_bytes = (size_t)nv * EMBED * sizeof(unsigned short);
    const size_t need = d_bytes + kb_bytes + vb_bytes;

    if (ws_size < need || (nq % 128) || (nv % 128) || nv > 4096 || (nq % 2)) {
        uv_direct_kernel<<<nq, 256, 0, stream>>>(key, value, identity, ref3d, spatial, out);
        return;
    }

    unsigned short* D  = (unsigned short*)d_ws;
    unsigned short* kb = (unsigned short*)((char*)d_ws + d_bytes);
    unsigned short* vb = (unsigned short*)((char*)d_ws + d_bytes + kb_bytes);

    // Phase 1: convert key & value to bf16
    const int n4 = nq * EMBED / 4;
    cvt_kernel<<<(n4 + 255) / 256, 256, 0, stream>>>(
        (const float4*)key, (const float4*)value, (ushort4*)kb, (ushort4*)vb, n4);

    // Phase 2: D = key . value^T
    dim3 grid(nv / 128, nq / 128);
    gemm_nt_bf16<<<grid, 256, 0, stream>>>(kb, vb, D, nv);

    // Phase 3: bilinear gather + identity (2 queries per block)
    gather_kernel<<<nq / 2, 256, 0, stream>>>(D, identity, ref3d, spatial, out, nv);
}